// Round 9
// baseline (191.378 us; speedup 1.0000x reference)
//
#include <hip/hip_runtime.h>

typedef short bhalf8 __attribute__((ext_vector_type(8)));   // 8 x bf16 = 4 VGPRs
typedef float floatx4 __attribute__((ext_vector_type(4)));  // MFMA C/D frag

#define D_MODEL 1024
#define SEQ     2048
#define BATCH   2
#define NHEAD   16
#define DH      64

// global -> LDS direct DMA (m97: width 16 emits global_load_lds_dwordx4).
// LDS dest is WAVE-UNIFORM base; lane i lands at base + i*16 (no padding!).
#define GLDS(g, l) __builtin_amdgcn_global_load_lds( \
    (const __attribute__((address_space(1))) void*)(g), \
    (__attribute__((address_space(3))) void*)(l), 16, 0, 0)

static __device__ __forceinline__ short f2bf(float f) {
    unsigned u = __builtin_bit_cast(unsigned, f);
    u = (u + 0x7fffu + ((u >> 16) & 1u)) >> 16;   // RNE fp32 -> bf16
    return (short)u;
}
static __device__ __forceinline__ unsigned pack2(float a, float b) {
    return (unsigned)(unsigned short)f2bf(a) | ((unsigned)(unsigned short)f2bf(b) << 16);
}
// HW packed fp32->bf16 (RNE); no builtin on gfx950, inline asm per T12 recipe.
static __device__ __forceinline__ unsigned cvt_pk_bf16(float lo, float hi) {
    unsigned r;
    asm("v_cvt_pk_bf16_f32 %0, %1, %2" : "=v"(r) : "v"(lo), "v"(hi));
    return r;
}

// ---------------------------------------------------------------------------
// Merged cast kernel: bid<2048 -> x (fp32->bf16); else wq/wk/wv/wo into wall.
// ---------------------------------------------------------------------------
__global__ __launch_bounds__(256) void cast_all(const float* __restrict__ x,
                                                const float* __restrict__ wq,
                                                const float* __restrict__ wk,
                                                const float* __restrict__ wv,
                                                const float* __restrict__ wo,
                                                short* __restrict__ xb,
                                                short* __restrict__ wall) {
    const int bid = blockIdx.x;
    const float* s;
    short* d;
    int i;
    if (bid < 2048) {
        s = x; d = xb;
        i = (bid * 256 + threadIdx.x) * 8;
    } else {
        const int wb = bid - 2048;           // 0..2047
        const int which = wb >> 9;           // 0..3
        s = (which == 0) ? wq : (which == 1) ? wk : (which == 2) ? wv : wo;
        d = wall + (size_t)which * (D_MODEL * D_MODEL);
        i = ((wb & 511) * 256 + threadIdx.x) * 8;
    }
    float4 a = *(const float4*)(s + i);
    float4 b = *(const float4*)(s + i + 4);
    uint4 u = {pack2(a.x, a.y), pack2(a.z, a.w), pack2(b.x, b.y), pack2(b.z, b.w)};
    *(uint4*)(d + i) = u;
}

// ---------------------------------------------------------------------------
// Fused QKV GEMM v2 — 256x256 tile, BK=32, RING-OF-3 counted-vmcnt pipeline.
// (unchanged from round 8 — dropped out of top-5, < 52.8 us)
// ---------------------------------------------------------------------------
#define MFMA_BF16 __builtin_amdgcn_mfma_f32_16x16x32_bf16

#define QISSUE(kt, s) do {                                                    \
    char* ab_ = pool + (s) * 16384 + (w * 32) * 64;                           \
    char* bb_ = pool + 49152 + (s) * 16384 + (w * 32) * 64;                   \
    GLDS(Ag + (size_t)(kt) * 32, ab_);                                        \
    GLDS(Ag + (size_t)(kt) * 32 + 16 * 1024, ab_ + 1024);                     \
    GLDS(Wg + (size_t)(kt) * 32, bb_);                                        \
    GLDS(Wg + (size_t)(kt) * 32 + 16 * 1024, bb_ + 1024);                     \
} while (0)

#define QCOMP(s) do {                                                         \
    const short(*As_)[32] = (const short(*)[32])(pool + (s) * 16384);         \
    const short(*Bs_)[32] = (const short(*)[32])(pool + 49152 + (s) * 16384); \
    bhalf8 af_[8], bf_[4];                                                    \
    _Pragma("unroll")                                                         \
    for (int m_ = 0; m_ < 8; ++m_)                                            \
        af_[m_] = *(const bhalf8*)&As_[wr * 128 + m_ * 16 + l16][quad * 8];   \
    _Pragma("unroll")                                                         \
    for (int n_ = 0; n_ < 4; ++n_)                                            \
        bf_[n_] = *(const bhalf8*)&Bs_[wc * 64 + n_ * 16 + l16][quad * 8];    \
    __builtin_amdgcn_s_setprio(1);                                            \
    _Pragma("unroll")                                                         \
    for (int m_ = 0; m_ < 8; ++m_)                                            \
        _Pragma("unroll")                                                     \
        for (int n_ = 0; n_ < 4; ++n_)                                        \
            acc[m_][n_] = MFMA_BF16(af_[m_], bf_[n_], acc[m_][n_], 0, 0, 0);  \
    __builtin_amdgcn_s_setprio(0);                                            \
} while (0)

__global__ __launch_bounds__(512) void gemm_qkv2(const short* __restrict__ A,
                                                 const short* __restrict__ W,
                                                 short* __restrict__ Qo,
                                                 short* __restrict__ Ko,
                                                 short* __restrict__ Vt) {
    __shared__ __align__(16) char pool[98304];   // ring 96 KB; epilogue aliases
    const int t    = threadIdx.x;
    const int w    = t >> 6, lane = t & 63, quad = lane >> 4, l16 = lane & 15;
    const int wr   = w >> 2, wc = w & 3;
    const int bm   = blockIdx.x * 256;
    const int by   = (int)blockIdx.y;
    const int bn   = by * 256;

    const short* Ag = A + (size_t)(bm + w * 32 + (lane >> 2)) * 1024 + (lane & 3) * 8;
    const short* Wg = W + (size_t)(bn + w * 32 + (lane >> 2)) * 1024 + (lane & 3) * 8;

    floatx4 acc[8][4];
#pragma unroll
    for (int m = 0; m < 8; ++m)
#pragma unroll
        for (int n = 0; n < 4; ++n) {
            floatx4 z = {0.f, 0.f, 0.f, 0.f};
            acc[m][n] = z;
        }

    QISSUE(0, 0);
    QISSUE(1, 1);
    int sc_ = 0, sn_ = 2;
#pragma unroll 1
    for (int kt = 0; kt < 30; ++kt) {
        asm volatile("s_waitcnt vmcnt(4)" ::: "memory");  // tile kt landed
        __builtin_amdgcn_s_barrier();
        QISSUE(kt + 2, sn_);
        QCOMP(sc_);
        sc_ = (sc_ == 2) ? 0 : sc_ + 1;
        sn_ = (sn_ == 2) ? 0 : sn_ + 1;
    }
    asm volatile("s_waitcnt vmcnt(4)" ::: "memory");
    __builtin_amdgcn_s_barrier();
    QCOMP(sc_);
    sc_ = (sc_ == 2) ? 0 : sc_ + 1;
    asm volatile("s_waitcnt vmcnt(0)" ::: "memory");
    __builtin_amdgcn_s_barrier();
    QCOMP(sc_);

    // ---- epilogue: 2 halves of 128 rows staged in dead ring LDS ----
    __syncthreads();
    short (*Ct)[268] = (short(*)[268])pool;               // 128x268x2 = 68608 B
    if (by < 8) {
        short* outp = (by < 4) ? Qo : Ko;
        const int colbase = (by < 4) ? bn : bn - 1024;
        for (int hh = 0; hh < 2; ++hh) {
            if (wr == hh) {
#pragma unroll
                for (int m = 0; m < 8; ++m)
#pragma unroll
                    for (int n = 0; n < 4; ++n)
#pragma unroll
                        for (int g = 0; g < 4; ++g)
                            Ct[m * 16 + quad * 4 + g][wc * 64 + n * 16 + l16] =
                                f2bf(acc[m][n][g]);
            }
            __syncthreads();
            {
                const int r = t >> 2, c0 = (t & 3) * 64;
#pragma unroll
                for (int p = 0; p < 8; ++p)
                    *(uint4*)(outp + (size_t)(bm + hh * 128 + r) * 1024 +
                              colbase + c0 + p * 8) =
                        *(const uint4*)&Ct[r][c0 + p * 8];
            }
            __syncthreads();
        }
    } else {
        const int nbase = bn - 2048;
        for (int hh = 0; hh < 2; ++hh) {
            if ((wc >> 1) == hh) {
#pragma unroll
                for (int m = 0; m < 8; ++m)
#pragma unroll
                    for (int n = 0; n < 4; ++n)
#pragma unroll
                        for (int g = 0; g < 4; ++g)
                            Ct[wc * 64 + n * 16 + l16 - hh * 128]
                              [wr * 128 + m * 16 + quad * 4 + g] =
                                f2bf(acc[m][n][g]);
            }
            __syncthreads();
            {
                const int r = t >> 2, c0 = (t & 3) * 64;
#pragma unroll
                for (int p = 0; p < 8; ++p)
                    *(uint4*)(Vt + (size_t)(nbase + hh * 128 + r) * 4096 +
                              bm + c0 + p * 8) =
                        *(const uint4*)&Ct[r][c0 + p * 8];
            }
            __syncthreads();
        }
    }
}

// ---------------------------------------------------------------------------
// O-projection GEMM, m97-style: A = Y [4096][1024] bf16, W = wob, C fp32.
// ---------------------------------------------------------------------------
__global__ __launch_bounds__(256) void gemm_o(const short* __restrict__ A,
                                              const short* __restrict__ W,
                                              float* __restrict__ C) {
    __shared__ __align__(16) char pool[34816];
    short (*As)[64] = (short(*)[64])pool;             // 128x64 = 16384 B
    short (*Bs)[64] = (short(*)[64])(pool + 16384);   //  64x64 =  8192 B
    const int t    = threadIdx.x;
    const int wave = t >> 6, lane = t & 63, quad = lane >> 4, l16 = lane & 15;
    const int bm = blockIdx.x * 128, bn = blockIdx.y * 64;
    const int qm = (wave >> 1) * 64, qn = (wave & 1) * 32;

    const int lrow = lane >> 3, lcol = (lane & 7) * 8;
    const short* Ag = A + (size_t)(bm + wave * 32 + lrow) * 1024 + lcol;
    const short* Wg = W + (size_t)(bn + wave * 16 + lrow) * 1024 + lcol;
    short* Al = &As[wave * 32][0];
    short* Bl = &Bs[wave * 16][0];

    floatx4 acc[4][2];
#pragma unroll
    for (int i = 0; i < 4; ++i)
#pragma unroll
        for (int j = 0; j < 2; ++j) {
            floatx4 z = {0.f, 0.f, 0.f, 0.f};
            acc[i][j] = z;
        }

    for (int k0 = 0; k0 < 1024; k0 += 64) {
        __syncthreads();
#pragma unroll
        for (int j = 0; j < 4; ++j)
            GLDS(Ag + k0 + (size_t)j * 8 * 1024, Al + j * 8 * 64);
#pragma unroll
        for (int j = 0; j < 2; ++j)
            GLDS(Wg + k0 + (size_t)j * 8 * 1024, Bl + j * 8 * 64);
        __syncthreads();
#pragma unroll
        for (int kk = 0; kk < 64; kk += 32) {
            bhalf8 af[4], bfr[2];
#pragma unroll
            for (int im = 0; im < 4; ++im)
                af[im] = *(const bhalf8*)&As[qm + im * 16 + l16][kk + quad * 8];
#pragma unroll
            for (int jn = 0; jn < 2; ++jn)
                bfr[jn] = *(const bhalf8*)&Bs[qn + jn * 16 + l16][kk + quad * 8];
#pragma unroll
            for (int im = 0; im < 4; ++im)
#pragma unroll
                for (int jn = 0; jn < 2; ++jn)
                    acc[im][jn] = __builtin_amdgcn_mfma_f32_16x16x32_bf16(
                        af[im], bfr[jn], acc[im][jn], 0, 0, 0);
        }
    }

    // ---- fp32 LDS epilogue, line-complete stores ----
    __syncthreads();
    float (*Ctf)[68] = (float(*)[68])pool;            // 128x68x4 = 34816 B
#pragma unroll
    for (int im = 0; im < 4; ++im)
#pragma unroll
        for (int jn = 0; jn < 2; ++jn)
#pragma unroll
            for (int g = 0; g < 4; ++g)
                Ctf[qm + im * 16 + quad * 4 + g][qn + jn * 16 + l16] = acc[im][jn][g];
    __syncthreads();
#pragma unroll
    for (int pass = 0; pass < 8; ++pass) {
        const int r = (t >> 4) + pass * 16;
        const int c = (t & 15) * 4;
        float4 u = *(const float4*)&Ctf[r][c];
        *(float4*)(C + (size_t)(bm + r) * 1024 + bn + c) = u;
    }
}

// ---------------------------------------------------------------------------
// Flash attention v15 — 2 k-teams per block: tile-15's 32-phase serial chain
// halved to 16 by splitting the k-range across independent accumulators.
// v14 post-mortem: 52.8 us = worst-CU 32 barrier-phases (heavy block runs
// alone after light dies); phase ~4K cy = chunk chain. Fixed-CB softmax =>
// k-partials additive => split WITHIN a block: 8 waves = 2 teams x 4;
// team T covers k in [T*nc/2,(T+1)*nc/2) for the SAME 128 rows (QBLK=32/
// wave, im 0..1); each team stages its own KVBLK=32 chunks (dbuf). Equal
// chunk counts per team => lockstep through shared barriers => block
// makespan = (qt+1) units (tile 15: 16, was 32). Combine: team 1 parks
// (o,lsum) in LDS (aliased, post-loop), team 0 adds + stores.
// Grid 512 = 32 bh x 16 qt; bid<256 -> qt=bid>>5 (0..7), else 15-((bid-256)
// >>5) (15..8): CU c hosts {qt, 15-qt} = uniform 17 units. bid%8 = bh%8
// keeps head->XCD L2 locality. Fully-masked chunks skip compute (wave-
// uniform branch). V-frags read AFTER softmax (VGPR<128 guardrail, v9/v11
// lesson: plain __launch_bounds__(512), no min-waves hint).
// LDS: Ks[2][2][32][72] 18432 + Vs[2][2][64][40] 20480 + Ps[8][32][40]
// 20480 = 59392 B -> 2 blocks/CU. Cmb[4][64][44] f32 (45056) aliases pool.
// ---------------------------------------------------------------------------

// Staging (per team: 256 thr, 16B each): K chunk [32 k][64 d] 4KB,
// V^T chunk [64 d][32 k] 4KB.
#define STAGE_LOAD15(kk) do {                                                 \
    kreg = *(const uint4*)(Kbase + (size_t)((kk) + skr) * 1024 + skc);        \
    vreg = *(const uint4*)(Vbase + (size_t)svr * 4096 + (kk) + svc);          \
    } while (0)

#define STAGE_WRITE15(bufv) do {                                              \
    *(uint4*)&Ks[team][bufv][skr][skc] = kreg;                                \
    *(uint4*)&Vs[team][bufv][svr][svc] = vreg;                                \
    } while (0)

// One 32-k chunk for one wave (32 q-rows at qw_), K/V from team's LDS buf.
#define CHUNK15(bufv, k0v) do {                                               \
    bhalf8 kf_[2][2];                                                         \
    _Pragma("unroll")                                                         \
    for (int jn_ = 0; jn_ < 2; ++jn_) {                                       \
        kf_[jn_][0] = *(const bhalf8*)&Ks[team][bufv][jn_ * 16 + l16][quad * 8]; \
        kf_[jn_][1] = *(const bhalf8*)&Ks[team][bufv][jn_ * 16 + l16][32 + quad * 8]; \
    }                                                                         \
    floatx4 s_[2][2];                                                         \
    _Pragma("unroll")                                                         \
    for (int im_ = 0; im_ < 2; ++im_)                                         \
        _Pragma("unroll")                                                     \
        for (int jn_ = 0; jn_ < 2; ++jn_) {                                   \
            floatx4 z_ = {0.f, 0.f, 0.f, 0.f};                                \
            z_ = MFMA_BF16(qf[im_][0], kf_[jn_][0], z_, 0, 0, 0);             \
            z_ = MFMA_BF16(qf[im_][1], kf_[jn_][1], z_, 0, 0, 0);             \
            s_[im_][jn_] = z_;                                                \
        }                                                                     \
    const bool partial_ = ((k0v) + 32 > qw_);                                 \
    _Pragma("unroll")                                                         \
    for (int im_ = 0; im_ < 2; ++im_)                                         \
        _Pragma("unroll")                                                     \
        for (int g_ = 0; g_ < 4; ++g_) {                                      \
            const int rr_ = im_ * 16 + quad * 4 + g_;                         \
            const int qrow_ = qw_ + rr_;                                      \
            float e0_ = exp2f(s_[im_][0][g_] * KS - CB);                      \
            float e1_ = exp2f(s_[im_][1][g_] * KS - CB);                      \
            if (partial_) {                                                   \
                if ((k0v) + l16 > qrow_)      e0_ = 0.f;                      \
                if ((k0v) + 16 + l16 > qrow_) e1_ = 0.f;                      \
            }                                                                 \
            lsum[im_][g_] += e0_ + e1_;                                       \
            unsigned r01_ = cvt_pk_bf16(e0_, e1_);                            \
            Ps[wave][rr_][l16]      = (short)r01_;                            \
            Ps[wave][rr_][16 + l16] = (short)(r01_ >> 16);                    \
        }                                                                     \
    /* same-wave LDS RAW: compiler inserts lgkmcnt drain before reads */      \
    bhalf8 vf_[4];                                                            \
    _Pragma("unroll")                                                         \
    for (int nd_ = 0; nd_ < 4; ++nd_)                                         \
        vf_[nd_] = *(const bhalf8*)&Vs[team][bufv][nd_ * 16 + l16][quad * 8]; \
    bhalf8 ap_[2];                                                            \
    _Pragma("unroll")                                                         \
    for (int im_ = 0; im_ < 2; ++im_)                                         \
        ap_[im_] = *(const bhalf8*)&Ps[wave][im_ * 16 + l16][quad * 8];       \
    _Pragma("unroll")                                                         \
    for (int im_ = 0; im_ < 2; ++im_)                                         \
        _Pragma("unroll")                                                     \
        for (int nd_ = 0; nd_ < 4; ++nd_)                                     \
            o[im_][nd_] = MFMA_BF16(ap_[im_], vf_[nd_], o[im_][nd_], 0, 0, 0); \
} while (0)

__global__ __launch_bounds__(512) void attn_v15(const short* __restrict__ Qo,
                                                const short* __restrict__ Ko,
                                                const short* __restrict__ Vt,
                                                short* __restrict__ Y) {
    __shared__ __align__(16) char pool[59392];
    short (*Ks)[2][32][72] = (short(*)[2][32][72])pool;            // [team][buf]
    short (*Vs)[2][64][40] = (short(*)[2][64][40])(pool + 18432);  // [team][buf]
    short (*Ps)[32][40]    = (short(*)[32][40])(pool + 38912);     // [wave]
    float (*Cmb)[64][44]   = (float(*)[64][44])pool;               // post-loop alias

    const int t    = threadIdx.x;
    const int wave = t >> 6, lane = t & 63, quad = lane >> 4, l16 = lane & 15;
    const int team = t >> 8, wt = wave & 3, tt = t & 255;
    const int bid  = (int)blockIdx.x;
    const int bh   = bid & 31;                      // bid%8 = bh%8: XCD-tied
    const int qt   = (bid < 256) ? (bid >> 5) : (15 - ((bid - 256) >> 5));
    const int b = bh >> 4, h = bh & 15;
    const int nct   = (qt + 1) * 2;                 // chunks per team
    const int kbase = team * nct * 32;              // team's k start

    const short* Qbase = Qo + (size_t)b * SEQ * 1024 + h * 64;
    const short* Kbase = Ko + (size_t)b * SEQ * 1024 + h * 64;
    const short* Vbase = Vt + (size_t)h * 64 * 4096 + (size_t)b * SEQ;

    const int skr = tt >> 3, skc = (tt & 7) * 8;    // K staging map (32x64)
    const int svr = tt >> 2, svc = (tt & 3) * 8;    // V staging map (64x32)

    const float KS = 0.125f * 1.44269504f;          // score scale * log2(e)
    const float CB = 12.0f * 1.44269504f;           // fixed softmax offset

    const int qw_ = qt * 128 + wt * 32;             // wave's 32 q-rows
    bhalf8 qf[2][2];
#pragma unroll
    for (int im = 0; im < 2; ++im) {
        const short* qr = Qbase + (size_t)(qw_ + im * 16 + l16) * 1024;
        qf[im][0] = *(const bhalf8*)(qr + quad * 8);
        qf[im][1] = *(const bhalf8*)(qr + 32 + quad * 8);
    }

    float lsum[2][4];
    floatx4 o[2][4];
#pragma unroll
    for (int im = 0; im < 2; ++im) {
#pragma unroll
        for (int g = 0; g < 4; ++g) lsum[im][g] = 0.f;
#pragma unroll
        for (int nd = 0; nd < 4; ++nd) {
            floatx4 z = {0.f, 0.f, 0.f, 0.f};
            o[im][nd] = z;
        }
    }

    uint4 kreg, vreg;
    STAGE_LOAD15(kbase);
    STAGE_WRITE15(0);
    if (nct > 1) STAGE_LOAD15(kbase + 32);
    __syncthreads();
#pragma unroll 1
    for (int i = 0; i < nct; ++i) {
        const int buf = i & 1;
        if (i + 1 < nct) STAGE_WRITE15(buf ^ 1);
        if (i + 2 < nct) STAGE_LOAD15(kbase + (i + 2) * 32);
        const int k0 = kbase + i * 32;
        if (k0 <= qw_ + 31) {              // wave-uniform: skip fully-masked
            CHUNK15(buf, k0);
        }
        __syncthreads();
    }

    // ---- combine: team 1 parks partials (LDS dead after final barrier) ----
    if (team == 1) {
        float* cp = &Cmb[wt][lane][0];
#pragma unroll
        for (int im = 0; im < 2; ++im)
#pragma unroll
            for (int nd = 0; nd < 4; ++nd)
                *(floatx4*)(cp + (im * 4 + nd) * 4) = o[im][nd];
#pragma unroll
        for (int im = 0; im < 2; ++im)
#pragma unroll
            for (int g = 0; g < 4; ++g)
                cp[32 + im * 4 + g] = lsum[im][g];
    }
    __syncthreads();
    if (team == 0) {
        const float* cp = &Cmb[wt][lane][0];
#pragma unroll
        for (int im = 0; im < 2; ++im)
#pragma unroll
            for (int nd = 0; nd < 4; ++nd)
                o[im][nd] += *(const floatx4*)(cp + (im * 4 + nd) * 4);
#pragma unroll
        for (int im = 0; im < 2; ++im)
#pragma unroll
            for (int g = 0; g < 4; ++g) {
                float r = lsum[im][g] + cp[32 + im * 4 + g];
                r += __shfl_xor(r, 1, 64);
                r += __shfl_xor(r, 2, 64);
                r += __shfl_xor(r, 4, 64);
                r += __shfl_xor(r, 8, 64);
                const float iv = 1.0f / r;
                const int qrow = qw_ + im * 16 + quad * 4 + g;
#pragma unroll
                for (int nd = 0; nd < 4; ++nd)
                    Y[(size_t)(b * SEQ + qrow) * 1024 + h * 64 + nd * 16 + l16] =
                        f2bf(o[im][nd][g] * iv);
            }
    }
}

// ---------------------------------------------------------------------------
extern "C" void kernel_launch(void* const* d_in, const int* in_sizes, int n_in,
                              void* d_out, int out_size, void* d_ws, size_t ws_size,
                              hipStream_t stream) {
    const float* x  = (const float*)d_in[0];
    const float* wq = (const float*)d_in[1];
    const float* wk = (const float*)d_in[2];
    const float* wv = (const float*)d_in[3];
    const float* wo = (const float*)d_in[4];

    short* xb   = (short*)d_ws;
    short* Qo   = xb + (size_t)4096 * 1024;
    short* Ko   = Qo + (size_t)4096 * 1024;
    short* Vt   = Ko + (size_t)4096 * 1024;
    short* wall = Vt + (size_t)1024 * 4096;
    short* wob  = wall + (size_t)3 * 1024 * 1024;

    cast_all<<<dim3(4096), 256, 0, stream>>>(x, wq, wk, wv, wo, xb, wall);
    gemm_qkv2<<<dim3(16, 12), 512, 0, stream>>>(xb, wall, Qo, Ko, Vt);
    attn_v15<<<dim3(512), 512, 0, stream>>>(Qo, Ko, Vt, xb);
    gemm_o<<<dim3(32, 16), 256, 0, stream>>>(xb, wob, (float*)d_out);
}

// Round 10
// 190.370 us; speedup vs baseline: 1.0053x; 1.0053x over previous
//
#include <hip/hip_runtime.h>

typedef short bhalf8 __attribute__((ext_vector_type(8)));   // 8 x bf16 = 4 VGPRs
typedef float floatx4 __attribute__((ext_vector_type(4)));  // MFMA C/D frag

#define D_MODEL 1024
#define SEQ     2048
#define BATCH   2
#define NHEAD   16
#define DH      64

// global -> LDS direct DMA (m97: width 16 emits global_load_lds_dwordx4).
// LDS dest is WAVE-UNIFORM base; lane i lands at base + i*16 (no padding!).
#define GLDS(g, l) __builtin_amdgcn_global_load_lds( \
    (const __attribute__((address_space(1))) void*)(g), \
    (__attribute__((address_space(3))) void*)(l), 16, 0, 0)

static __device__ __forceinline__ short f2bf(float f) {
    unsigned u = __builtin_bit_cast(unsigned, f);
    u = (u + 0x7fffu + ((u >> 16) & 1u)) >> 16;   // RNE fp32 -> bf16
    return (short)u;
}
static __device__ __forceinline__ unsigned pack2(float a, float b) {
    return (unsigned)(unsigned short)f2bf(a) | ((unsigned)(unsigned short)f2bf(b) << 16);
}
// HW packed fp32->bf16 (RNE); no builtin on gfx950, inline asm per T12 recipe.
static __device__ __forceinline__ unsigned cvt_pk_bf16(float lo, float hi) {
    unsigned r;
    asm("v_cvt_pk_bf16_f32 %0, %1, %2" : "=v"(r) : "v"(lo), "v"(hi));
    return r;
}

// ---------------------------------------------------------------------------
// Merged cast kernel: bid<2048 -> x (fp32->bf16); else wq/wk/wv/wo into wall.
// ---------------------------------------------------------------------------
__global__ __launch_bounds__(256) void cast_all(const float* __restrict__ x,
                                                const float* __restrict__ wq,
                                                const float* __restrict__ wk,
                                                const float* __restrict__ wv,
                                                const float* __restrict__ wo,
                                                short* __restrict__ xb,
                                                short* __restrict__ wall) {
    const int bid = blockIdx.x;
    const float* s;
    short* d;
    int i;
    if (bid < 2048) {
        s = x; d = xb;
        i = (bid * 256 + threadIdx.x) * 8;
    } else {
        const int wb = bid - 2048;           // 0..2047
        const int which = wb >> 9;           // 0..3
        s = (which == 0) ? wq : (which == 1) ? wk : (which == 2) ? wv : wo;
        d = wall + (size_t)which * (D_MODEL * D_MODEL);
        i = ((wb & 511) * 256 + threadIdx.x) * 8;
    }
    float4 a = *(const float4*)(s + i);
    float4 b = *(const float4*)(s + i + 4);
    uint4 u = {pack2(a.x, a.y), pack2(a.z, a.w), pack2(b.x, b.y), pack2(b.z, b.w)};
    *(uint4*)(d + i) = u;
}

// ---------------------------------------------------------------------------
// Fused QKV GEMM v2 — 256x256 tile, BK=32, RING-OF-3 counted-vmcnt pipeline.
// (unchanged — dropped out of top-5)
// ---------------------------------------------------------------------------
#define MFMA_BF16 __builtin_amdgcn_mfma_f32_16x16x32_bf16

#define QISSUE(kt, s) do {                                                    \
    char* ab_ = pool + (s) * 16384 + (w * 32) * 64;                           \
    char* bb_ = pool + 49152 + (s) * 16384 + (w * 32) * 64;                   \
    GLDS(Ag + (size_t)(kt) * 32, ab_);                                        \
    GLDS(Ag + (size_t)(kt) * 32 + 16 * 1024, ab_ + 1024);                     \
    GLDS(Wg + (size_t)(kt) * 32, bb_);                                        \
    GLDS(Wg + (size_t)(kt) * 32 + 16 * 1024, bb_ + 1024);                     \
} while (0)

#define QCOMP(s) do {                                                         \
    const short(*As_)[32] = (const short(*)[32])(pool + (s) * 16384);         \
    const short(*Bs_)[32] = (const short(*)[32])(pool + 49152 + (s) * 16384); \
    bhalf8 af_[8], bf_[4];                                                    \
    _Pragma("unroll")                                                         \
    for (int m_ = 0; m_ < 8; ++m_)                                            \
        af_[m_] = *(const bhalf8*)&As_[wr * 128 + m_ * 16 + l16][quad * 8];   \
    _Pragma("unroll")                                                         \
    for (int n_ = 0; n_ < 4; ++n_)                                            \
        bf_[n_] = *(const bhalf8*)&Bs_[wc * 64 + n_ * 16 + l16][quad * 8];    \
    __builtin_amdgcn_s_setprio(1);                                            \
    _Pragma("unroll")                                                         \
    for (int m_ = 0; m_ < 8; ++m_)                                            \
        _Pragma("unroll")                                                     \
        for (int n_ = 0; n_ < 4; ++n_)                                        \
            acc[m_][n_] = MFMA_BF16(af_[m_], bf_[n_], acc[m_][n_], 0, 0, 0);  \
    __builtin_amdgcn_s_setprio(0);                                            \
} while (0)

__global__ __launch_bounds__(512) void gemm_qkv2(const short* __restrict__ A,
                                                 const short* __restrict__ W,
                                                 short* __restrict__ Qo,
                                                 short* __restrict__ Ko,
                                                 short* __restrict__ Vt) {
    __shared__ __align__(16) char pool[98304];   // ring 96 KB; epilogue aliases
    const int t    = threadIdx.x;
    const int w    = t >> 6, lane = t & 63, quad = lane >> 4, l16 = lane & 15;
    const int wr   = w >> 2, wc = w & 3;
    const int bm   = blockIdx.x * 256;
    const int by   = (int)blockIdx.y;
    const int bn   = by * 256;

    const short* Ag = A + (size_t)(bm + w * 32 + (lane >> 2)) * 1024 + (lane & 3) * 8;
    const short* Wg = W + (size_t)(bn + w * 32 + (lane >> 2)) * 1024 + (lane & 3) * 8;

    floatx4 acc[8][4];
#pragma unroll
    for (int m = 0; m < 8; ++m)
#pragma unroll
        for (int n = 0; n < 4; ++n) {
            floatx4 z = {0.f, 0.f, 0.f, 0.f};
            acc[m][n] = z;
        }

    QISSUE(0, 0);
    QISSUE(1, 1);
    int sc_ = 0, sn_ = 2;
#pragma unroll 1
    for (int kt = 0; kt < 30; ++kt) {
        asm volatile("s_waitcnt vmcnt(4)" ::: "memory");  // tile kt landed
        __builtin_amdgcn_s_barrier();
        QISSUE(kt + 2, sn_);
        QCOMP(sc_);
        sc_ = (sc_ == 2) ? 0 : sc_ + 1;
        sn_ = (sn_ == 2) ? 0 : sn_ + 1;
    }
    asm volatile("s_waitcnt vmcnt(4)" ::: "memory");
    __builtin_amdgcn_s_barrier();
    QCOMP(sc_);
    sc_ = (sc_ == 2) ? 0 : sc_ + 1;
    asm volatile("s_waitcnt vmcnt(0)" ::: "memory");
    __builtin_amdgcn_s_barrier();
    QCOMP(sc_);

    // ---- epilogue: 2 halves of 128 rows staged in dead ring LDS ----
    __syncthreads();
    short (*Ct)[268] = (short(*)[268])pool;               // 128x268x2 = 68608 B
    if (by < 8) {
        short* outp = (by < 4) ? Qo : Ko;
        const int colbase = (by < 4) ? bn : bn - 1024;
        for (int hh = 0; hh < 2; ++hh) {
            if (wr == hh) {
#pragma unroll
                for (int m = 0; m < 8; ++m)
#pragma unroll
                    for (int n = 0; n < 4; ++n)
#pragma unroll
                        for (int g = 0; g < 4; ++g)
                            Ct[m * 16 + quad * 4 + g][wc * 64 + n * 16 + l16] =
                                f2bf(acc[m][n][g]);
            }
            __syncthreads();
            {
                const int r = t >> 2, c0 = (t & 3) * 64;
#pragma unroll
                for (int p = 0; p < 8; ++p)
                    *(uint4*)(outp + (size_t)(bm + hh * 128 + r) * 1024 +
                              colbase + c0 + p * 8) =
                        *(const uint4*)&Ct[r][c0 + p * 8];
            }
            __syncthreads();
        }
    } else {
        const int nbase = bn - 2048;
        for (int hh = 0; hh < 2; ++hh) {
            if ((wc >> 1) == hh) {
#pragma unroll
                for (int m = 0; m < 8; ++m)
#pragma unroll
                    for (int n = 0; n < 4; ++n)
#pragma unroll
                        for (int g = 0; g < 4; ++g)
                            Ct[wc * 64 + n * 16 + l16 - hh * 128]
                              [wr * 128 + m * 16 + quad * 4 + g] =
                                f2bf(acc[m][n][g]);
            }
            __syncthreads();
            {
                const int r = t >> 2, c0 = (t & 3) * 64;
#pragma unroll
                for (int p = 0; p < 8; ++p)
                    *(uint4*)(Vt + (size_t)(nbase + hh * 128 + r) * 4096 +
                              bm + c0 + p * 8) =
                        *(const uint4*)&Ct[r][c0 + p * 8];
            }
            __syncthreads();
        }
    }
}

// ---------------------------------------------------------------------------
// O-projection GEMM, m97-style: A = Y [4096][1024] bf16, W = wob, C fp32.
// ---------------------------------------------------------------------------
__global__ __launch_bounds__(256) void gemm_o(const short* __restrict__ A,
                                              const short* __restrict__ W,
                                              float* __restrict__ C) {
    __shared__ __align__(16) char pool[34816];
    short (*As)[64] = (short(*)[64])pool;             // 128x64 = 16384 B
    short (*Bs)[64] = (short(*)[64])(pool + 16384);   //  64x64 =  8192 B
    const int t    = threadIdx.x;
    const int wave = t >> 6, lane = t & 63, quad = lane >> 4, l16 = lane & 15;
    const int bm = blockIdx.x * 128, bn = blockIdx.y * 64;
    const int qm = (wave >> 1) * 64, qn = (wave & 1) * 32;

    const int lrow = lane >> 3, lcol = (lane & 7) * 8;
    const short* Ag = A + (size_t)(bm + wave * 32 + lrow) * 1024 + lcol;
    const short* Wg = W + (size_t)(bn + wave * 16 + lrow) * 1024 + lcol;
    short* Al = &As[wave * 32][0];
    short* Bl = &Bs[wave * 16][0];

    floatx4 acc[4][2];
#pragma unroll
    for (int i = 0; i < 4; ++i)
#pragma unroll
        for (int j = 0; j < 2; ++j) {
            floatx4 z = {0.f, 0.f, 0.f, 0.f};
            acc[i][j] = z;
        }

    for (int k0 = 0; k0 < 1024; k0 += 64) {
        __syncthreads();
#pragma unroll
        for (int j = 0; j < 4; ++j)
            GLDS(Ag + k0 + (size_t)j * 8 * 1024, Al + j * 8 * 64);
#pragma unroll
        for (int j = 0; j < 2; ++j)
            GLDS(Wg + k0 + (size_t)j * 8 * 1024, Bl + j * 8 * 64);
        __syncthreads();
#pragma unroll
        for (int kk = 0; kk < 64; kk += 32) {
            bhalf8 af[4], bfr[2];
#pragma unroll
            for (int im = 0; im < 4; ++im)
                af[im] = *(const bhalf8*)&As[qm + im * 16 + l16][kk + quad * 8];
#pragma unroll
            for (int jn = 0; jn < 2; ++jn)
                bfr[jn] = *(const bhalf8*)&Bs[qn + jn * 16 + l16][kk + quad * 8];
#pragma unroll
            for (int im = 0; im < 4; ++im)
#pragma unroll
                for (int jn = 0; jn < 2; ++jn)
                    acc[im][jn] = __builtin_amdgcn_mfma_f32_16x16x32_bf16(
                        af[im], bfr[jn], acc[im][jn], 0, 0, 0);
        }
    }

    // ---- fp32 LDS epilogue, line-complete stores ----
    __syncthreads();
    float (*Ctf)[68] = (float(*)[68])pool;            // 128x68x4 = 34816 B
#pragma unroll
    for (int im = 0; im < 4; ++im)
#pragma unroll
        for (int jn = 0; jn < 2; ++jn)
#pragma unroll
            for (int g = 0; g < 4; ++g)
                Ctf[qm + im * 16 + quad * 4 + g][qn + jn * 16 + l16] = acc[im][jn][g];
    __syncthreads();
#pragma unroll
    for (int pass = 0; pass < 8; ++pass) {
        const int r = (t >> 4) + pass * 16;
        const int c = (t & 15) * 4;
        float4 u = *(const float4*)&Ctf[r][c];
        *(float4*)(C + (size_t)(bm + r) * 1024 + bn + c) = u;
    }
}

// ---------------------------------------------------------------------------
// Flash attention v16 — 2 k-teams per block with KVBLK=64 (v15's bug fixed).
// v15 post-mortem: halving KVBLK to 32 cancelled the 2-team k-split —
// chunks/team stayed (qt+1)*2 = v14's 32 phases for tile 15; time unchanged
// (54.0 vs 52.8). Phase COUNT is the controlling variable; phase width is
// nearly free (chain ~4K cy, only ~40% busy).
// v16: teams keep KVBLK=64 -> nct = qt+1 phases (tile 15: 16, was 32);
// CU pair {qt, 15-qt} = 17 phase-units total (was 34). To fit 2 blocks/CU:
// K/V single-buffered per team with REGISTER prefetch (T14): loads for
// chunk i+1 issued right after staging chunk i, land during compute;
// ds_write after the barrier. LDS: Ks[2][64][72] 18432 + Vs[2][64][72]
// 18432 + Ps[8][32][72] 36864 = 73728 B -> 2 blocks/CU (147456 <= 163840).
// Per wave per chunk: 32 q-rows x 64 k: 16 S-MFMA + 32 exp2/lane + 16
// PV-MFMA. Fragment mappings identical to v13/v14 (harness-verified).
// Combine: barrier -> team 1 parks (o,lsum) in Cmb (aliases pool; barrier
// REQUIRED since Cmb overlaps Ps) -> barrier -> team 0 adds, reduces, stores.
// Grid 512 = 32 bh x 16 qt, bid%8 = bh%8 (head->XCD L2 locality);
// bid<256: qt=bid>>5 (0..7), else 15-((bid-256)>>5) (15..8) -> CU c hosts
// {qt, 15-qt}. VGPR guardrail: plain __launch_bounds__(512), no hint.
// ---------------------------------------------------------------------------

__global__ __launch_bounds__(512) void attn_v16(const short* __restrict__ Qo,
                                                const short* __restrict__ Ko,
                                                const short* __restrict__ Vt,
                                                short* __restrict__ Y) {
    __shared__ __align__(16) char pool[73728];
    short (*Ks)[64][72] = (short(*)[64][72])pool;              // [team][k][d]
    short (*Vs)[64][72] = (short(*)[64][72])(pool + 18432);    // [team][d][k]
    short (*Ps)[32][72] = (short(*)[32][72])(pool + 36864);    // [wave][row][k]
    float (*Cmb)[64][44] = (float(*)[64][44])pool;             // post-loop alias

    const int t    = threadIdx.x;
    const int wave = t >> 6, lane = t & 63, quad = lane >> 4, l16 = lane & 15;
    const int team = t >> 8, wt = wave & 3, tt = t & 255;
    const int bid  = (int)blockIdx.x;
    const int bh   = bid & 31;                      // bid%8 = bh%8: XCD-tied
    const int qt   = (bid < 256) ? (bid >> 5) : (15 - ((bid - 256) >> 5));
    const int b = bh >> 4, h = bh & 15;
    const int nct   = qt + 1;                       // chunks per team (64 k each)
    const int kbase = team * nct * 64;              // team's k start

    const short* Qbase = Qo + (size_t)b * SEQ * 1024 + h * 64;
    const short* Kbase = Ko + (size_t)b * SEQ * 1024 + h * 64;
    const short* Vbase = Vt + (size_t)h * 64 * 4096 + (size_t)b * SEQ;

    // staging map (per team, 256 thr): K chunk [64 k][64 d], V^T [64 d][64 k];
    // thread covers row tt>>2, cols (tt&3)*8 and +32 (2 x 16B each matrix).
    const int sr = tt >> 2, sc = (tt & 3) * 8;

    const float KS = 0.125f * 1.44269504f;          // score scale * log2(e)
    const float CB = 12.0f * 1.44269504f;           // fixed softmax offset

    const int qw_ = qt * 128 + wt * 32;             // wave's 32 q-rows
    bhalf8 qf[2][2];
#pragma unroll
    for (int im = 0; im < 2; ++im) {
        const short* qr = Qbase + (size_t)(qw_ + im * 16 + l16) * 1024;
        qf[im][0] = *(const bhalf8*)(qr + quad * 8);
        qf[im][1] = *(const bhalf8*)(qr + 32 + quad * 8);
    }

    float lsum[2][4];
    floatx4 o[2][4];
#pragma unroll
    for (int im = 0; im < 2; ++im) {
#pragma unroll
        for (int g = 0; g < 4; ++g) lsum[im][g] = 0.f;
#pragma unroll
        for (int nd = 0; nd < 4; ++nd) {
            floatx4 z = {0.f, 0.f, 0.f, 0.f};
            o[im][nd] = z;
        }
    }

    uint4 kr0, kr1, vr0, vr1;
    // prologue: chunk 0 -> regs
    kr0 = *(const uint4*)(Kbase + (size_t)(kbase + sr) * 1024 + sc);
    kr1 = *(const uint4*)(Kbase + (size_t)(kbase + sr) * 1024 + sc + 32);
    vr0 = *(const uint4*)(Vbase + (size_t)sr * 4096 + kbase + sc);
    vr1 = *(const uint4*)(Vbase + (size_t)sr * 4096 + kbase + sc + 32);

#pragma unroll 1
    for (int i = 0; i < nct; ++i) {
        __syncthreads();                 // prev compute done reading LDS
        *(uint4*)&Ks[team][sr][sc]      = kr0;
        *(uint4*)&Ks[team][sr][sc + 32] = kr1;
        *(uint4*)&Vs[team][sr][sc]      = vr0;
        *(uint4*)&Vs[team][sr][sc + 32] = vr1;
        __syncthreads();                 // chunk staged
        if (i + 1 < nct) {               // T14: next chunk -> regs, lands
            const int kn = kbase + (i + 1) * 64;          // during compute
            kr0 = *(const uint4*)(Kbase + (size_t)(kn + sr) * 1024 + sc);
            kr1 = *(const uint4*)(Kbase + (size_t)(kn + sr) * 1024 + sc + 32);
            vr0 = *(const uint4*)(Vbase + (size_t)sr * 4096 + kn + sc);
            vr1 = *(const uint4*)(Vbase + (size_t)sr * 4096 + kn + sc + 32);
        }
        const int k0 = kbase + i * 64;
        if (k0 <= qw_ + 31) {            // wave-uniform: skip fully-masked
            // ---- S = Q K^T (16 MFMA) ----
            bhalf8 kf[4][2];
#pragma unroll
            for (int jn = 0; jn < 4; ++jn) {
                kf[jn][0] = *(const bhalf8*)&Ks[team][jn * 16 + l16][quad * 8];
                kf[jn][1] = *(const bhalf8*)&Ks[team][jn * 16 + l16][32 + quad * 8];
            }
            const bool partial = (k0 + 64 > qw_);
#pragma unroll
            for (int im = 0; im < 2; ++im) {
                floatx4 s_[4];
#pragma unroll
                for (int jn = 0; jn < 4; ++jn) {
                    floatx4 z = {0.f, 0.f, 0.f, 0.f};
                    z = MFMA_BF16(qf[im][0], kf[jn][0], z, 0, 0, 0);
                    z = MFMA_BF16(qf[im][1], kf[jn][1], z, 0, 0, 0);
                    s_[jn] = z;
                }
                // ---- softmax (fixed-CB) + Ps write ----
#pragma unroll
                for (int g = 0; g < 4; ++g) {
                    const int rr = im * 16 + quad * 4 + g;
                    const int qrow = qw_ + rr;
                    float e0 = exp2f(s_[0][g] * KS - CB);
                    float e1 = exp2f(s_[1][g] * KS - CB);
                    float e2 = exp2f(s_[2][g] * KS - CB);
                    float e3 = exp2f(s_[3][g] * KS - CB);
                    if (partial) {
                        if (k0 + l16 > qrow)      e0 = 0.f;
                        if (k0 + 16 + l16 > qrow) e1 = 0.f;
                        if (k0 + 32 + l16 > qrow) e2 = 0.f;
                        if (k0 + 48 + l16 > qrow) e3 = 0.f;
                    }
                    lsum[im][g] += (e0 + e1) + (e2 + e3);
                    unsigned r01 = cvt_pk_bf16(e0, e1);
                    unsigned r23 = cvt_pk_bf16(e2, e3);
                    Ps[wave][rr][l16]      = (short)r01;
                    Ps[wave][rr][16 + l16] = (short)(r01 >> 16);
                    Ps[wave][rr][32 + l16] = (short)r23;
                    Ps[wave][rr][48 + l16] = (short)(r23 >> 16);
                }
            }
            // ---- O += P V (16 MFMA; same-wave LDS RAW, DS in-order) ----
            bhalf8 vf[4][2];
#pragma unroll
            for (int nd = 0; nd < 4; ++nd) {
                vf[nd][0] = *(const bhalf8*)&Vs[team][nd * 16 + l16][quad * 8];
                vf[nd][1] = *(const bhalf8*)&Vs[team][nd * 16 + l16][32 + quad * 8];
            }
#pragma unroll
            for (int im = 0; im < 2; ++im) {
                bhalf8 ap0 = *(const bhalf8*)&Ps[wave][im * 16 + l16][quad * 8];
                bhalf8 ap1 = *(const bhalf8*)&Ps[wave][im * 16 + l16][32 + quad * 8];
#pragma unroll
                for (int nd = 0; nd < 4; ++nd) {
                    o[im][nd] = MFMA_BF16(ap0, vf[nd][0], o[im][nd], 0, 0, 0);
                    o[im][nd] = MFMA_BF16(ap1, vf[nd][1], o[im][nd], 0, 0, 0);
                }
            }
        }
    }

    // ---- combine (Cmb aliases pool INCLUDING Ps -> barrier first) ----
    __syncthreads();
    if (team == 1) {
        float* cp = &Cmb[wt][lane][0];
#pragma unroll
        for (int im = 0; im < 2; ++im)
#pragma unroll
            for (int nd = 0; nd < 4; ++nd)
                *(floatx4*)(cp + (im * 4 + nd) * 4) = o[im][nd];
#pragma unroll
        for (int im = 0; im < 2; ++im)
#pragma unroll
            for (int g = 0; g < 4; ++g)
                cp[32 + im * 4 + g] = lsum[im][g];
    }
    __syncthreads();
    if (team == 0) {
        const float* cp = &Cmb[wt][lane][0];
#pragma unroll
        for (int im = 0; im < 2; ++im)
#pragma unroll
            for (int nd = 0; nd < 4; ++nd)
                o[im][nd] += *(const floatx4*)(cp + (im * 4 + nd) * 4);
#pragma unroll
        for (int im = 0; im < 2; ++im)
#pragma unroll
            for (int g = 0; g < 4; ++g) {
                float r = lsum[im][g] + cp[32 + im * 4 + g];
                r += __shfl_xor(r, 1, 64);
                r += __shfl_xor(r, 2, 64);
                r += __shfl_xor(r, 4, 64);
                r += __shfl_xor(r, 8, 64);
                const float iv = 1.0f / r;
                const int qrow = qw_ + im * 16 + quad * 4 + g;
#pragma unroll
                for (int nd = 0; nd < 4; ++nd)
                    Y[(size_t)(b * SEQ + qrow) * 1024 + h * 64 + nd * 16 + l16] =
                        f2bf(o[im][nd][g] * iv);
            }
    }
}

// ---------------------------------------------------------------------------
extern "C" void kernel_launch(void* const* d_in, const int* in_sizes, int n_in,
                              void* d_out, int out_size, void* d_ws, size_t ws_size,
                              hipStream_t stream) {
    const float* x  = (const float*)d_in[0];
    const float* wq = (const float*)d_in[1];
    const float* wk = (const float*)d_in[2];
    const float* wv = (const float*)d_in[3];
    const float* wo = (const float*)d_in[4];

    short* xb   = (short*)d_ws;
    short* Qo   = xb + (size_t)4096 * 1024;
    short* Ko   = Qo + (size_t)4096 * 1024;
    short* Vt   = Ko + (size_t)4096 * 1024;
    short* wall = Vt + (size_t)1024 * 4096;
    short* wob  = wall + (size_t)3 * 1024 * 1024;

    cast_all<<<dim3(4096), 256, 0, stream>>>(x, wq, wk, wv, wo, xb, wall);
    gemm_qkv2<<<dim3(16, 12), 512, 0, stream>>>(xb, wall, Qo, Ko, Vt);
    attn_v16<<<dim3(512), 512, 0, stream>>>(Qo, Ko, Vt, xb);
    gemm_o<<<dim3(32, 16), 256, 0, stream>>>(xb, wob, (float*)d_out);
}

// Round 11
// 189.534 us; speedup vs baseline: 1.0097x; 1.0044x over previous
//
#include <hip/hip_runtime.h>

typedef short bhalf8 __attribute__((ext_vector_type(8)));   // 8 x bf16 = 4 VGPRs
typedef short short4v __attribute__((ext_vector_type(4)));  // 4 x bf16 = 2 VGPRs
typedef unsigned uint4v __attribute__((ext_vector_type(4)));
typedef float floatx4 __attribute__((ext_vector_type(4)));  // MFMA C/D frag

#define D_MODEL 1024
#define SEQ     2048
#define BATCH   2
#define NHEAD   16
#define DH      64

// global -> LDS direct DMA (m97: width 16 emits global_load_lds_dwordx4).
// LDS dest is WAVE-UNIFORM base; lane i lands at base + i*16 (no padding!).
#define GLDS(g, l) __builtin_amdgcn_global_load_lds( \
    (const __attribute__((address_space(1))) void*)(g), \
    (__attribute__((address_space(3))) void*)(l), 16, 0, 0)

static __device__ __forceinline__ short f2bf(float f) {
    unsigned u = __builtin_bit_cast(unsigned, f);
    u = (u + 0x7fffu + ((u >> 16) & 1u)) >> 16;   // RNE fp32 -> bf16
    return (short)u;
}
static __device__ __forceinline__ unsigned pack2(float a, float b) {
    return (unsigned)(unsigned short)f2bf(a) | ((unsigned)(unsigned short)f2bf(b) << 16);
}
// HW packed fp32->bf16 (RNE); no builtin on gfx950, inline asm per T12 recipe.
static __device__ __forceinline__ unsigned cvt_pk_bf16(float lo, float hi) {
    unsigned r;
    asm("v_cvt_pk_bf16_f32 %0, %1, %2" : "=v"(r) : "v"(lo), "v"(hi));
    return r;
}

// ---------------------------------------------------------------------------
// Merged cast kernel: bid<2048 -> x (fp32->bf16); else wq/wk/wv/wo into wall.
// ---------------------------------------------------------------------------
__global__ __launch_bounds__(256) void cast_all(const float* __restrict__ x,
                                                const float* __restrict__ wq,
                                                const float* __restrict__ wk,
                                                const float* __restrict__ wv,
                                                const float* __restrict__ wo,
                                                short* __restrict__ xb,
                                                short* __restrict__ wall) {
    const int bid = blockIdx.x;
    const float* s;
    short* d;
    int i;
    if (bid < 2048) {
        s = x; d = xb;
        i = (bid * 256 + threadIdx.x) * 8;
    } else {
        const int wb = bid - 2048;           // 0..2047
        const int which = wb >> 9;           // 0..3
        s = (which == 0) ? wq : (which == 1) ? wk : (which == 2) ? wv : wo;
        d = wall + (size_t)which * (D_MODEL * D_MODEL);
        i = ((wb & 511) * 256 + threadIdx.x) * 8;
    }
    float4 a = *(const float4*)(s + i);
    float4 b = *(const float4*)(s + i + 4);
    uint4 u = {pack2(a.x, a.y), pack2(a.z, a.w), pack2(b.x, b.y), pack2(b.z, b.w)};
    *(uint4*)(d + i) = u;
}

// ---------------------------------------------------------------------------
// Fused QKV GEMM v2 — 256x256 tile, BK=32, RING-OF-3 counted-vmcnt pipeline.
// (unchanged — dropped out of top-5)
// ---------------------------------------------------------------------------
#define MFMA_BF16 __builtin_amdgcn_mfma_f32_16x16x32_bf16

#define QISSUE(kt, s) do {                                                    \
    char* ab_ = pool + (s) * 16384 + (w * 32) * 64;                           \
    char* bb_ = pool + 49152 + (s) * 16384 + (w * 32) * 64;                   \
    GLDS(Ag + (size_t)(kt) * 32, ab_);                                        \
    GLDS(Ag + (size_t)(kt) * 32 + 16 * 1024, ab_ + 1024);                     \
    GLDS(Wg + (size_t)(kt) * 32, bb_);                                        \
    GLDS(Wg + (size_t)(kt) * 32 + 16 * 1024, bb_ + 1024);                     \
} while (0)

#define QCOMP(s) do {                                                         \
    const short(*As_)[32] = (const short(*)[32])(pool + (s) * 16384);         \
    const short(*Bs_)[32] = (const short(*)[32])(pool + 49152 + (s) * 16384); \
    bhalf8 af_[8], bf_[4];                                                    \
    _Pragma("unroll")                                                         \
    for (int m_ = 0; m_ < 8; ++m_)                                            \
        af_[m_] = *(const bhalf8*)&As_[wr * 128 + m_ * 16 + l16][quad * 8];   \
    _Pragma("unroll")                                                         \
    for (int n_ = 0; n_ < 4; ++n_)                                            \
        bf_[n_] = *(const bhalf8*)&Bs_[wc * 64 + n_ * 16 + l16][quad * 8];    \
    __builtin_amdgcn_s_setprio(1);                                            \
    _Pragma("unroll")                                                         \
    for (int m_ = 0; m_ < 8; ++m_)                                            \
        _Pragma("unroll")                                                     \
        for (int n_ = 0; n_ < 4; ++n_)                                        \
            acc[m_][n_] = MFMA_BF16(af_[m_], bf_[n_], acc[m_][n_], 0, 0, 0);  \
    __builtin_amdgcn_s_setprio(0);                                            \
} while (0)

__global__ __launch_bounds__(512) void gemm_qkv2(const short* __restrict__ A,
                                                 const short* __restrict__ W,
                                                 short* __restrict__ Qo,
                                                 short* __restrict__ Ko,
                                                 short* __restrict__ Vt) {
    __shared__ __align__(16) char pool[98304];   // ring 96 KB; epilogue aliases
    const int t    = threadIdx.x;
    const int w    = t >> 6, lane = t & 63, quad = lane >> 4, l16 = lane & 15;
    const int wr   = w >> 2, wc = w & 3;
    const int bm   = blockIdx.x * 256;
    const int by   = (int)blockIdx.y;
    const int bn   = by * 256;

    const short* Ag = A + (size_t)(bm + w * 32 + (lane >> 2)) * 1024 + (lane & 3) * 8;
    const short* Wg = W + (size_t)(bn + w * 32 + (lane >> 2)) * 1024 + (lane & 3) * 8;

    floatx4 acc[8][4];
#pragma unroll
    for (int m = 0; m < 8; ++m)
#pragma unroll
        for (int n = 0; n < 4; ++n) {
            floatx4 z = {0.f, 0.f, 0.f, 0.f};
            acc[m][n] = z;
        }

    QISSUE(0, 0);
    QISSUE(1, 1);
    int sc_ = 0, sn_ = 2;
#pragma unroll 1
    for (int kt = 0; kt < 30; ++kt) {
        asm volatile("s_waitcnt vmcnt(4)" ::: "memory");  // tile kt landed
        __builtin_amdgcn_s_barrier();
        QISSUE(kt + 2, sn_);
        QCOMP(sc_);
        sc_ = (sc_ == 2) ? 0 : sc_ + 1;
        sn_ = (sn_ == 2) ? 0 : sn_ + 1;
    }
    asm volatile("s_waitcnt vmcnt(4)" ::: "memory");
    __builtin_amdgcn_s_barrier();
    QCOMP(sc_);
    sc_ = (sc_ == 2) ? 0 : sc_ + 1;
    asm volatile("s_waitcnt vmcnt(0)" ::: "memory");
    __builtin_amdgcn_s_barrier();
    QCOMP(sc_);

    // ---- epilogue: 2 halves of 128 rows staged in dead ring LDS ----
    __syncthreads();
    short (*Ct)[268] = (short(*)[268])pool;               // 128x268x2 = 68608 B
    if (by < 8) {
        short* outp = (by < 4) ? Qo : Ko;
        const int colbase = (by < 4) ? bn : bn - 1024;
        for (int hh = 0; hh < 2; ++hh) {
            if (wr == hh) {
#pragma unroll
                for (int m = 0; m < 8; ++m)
#pragma unroll
                    for (int n = 0; n < 4; ++n)
#pragma unroll
                        for (int g = 0; g < 4; ++g)
                            Ct[m * 16 + quad * 4 + g][wc * 64 + n * 16 + l16] =
                                f2bf(acc[m][n][g]);
            }
            __syncthreads();
            {
                const int r = t >> 2, c0 = (t & 3) * 64;
#pragma unroll
                for (int p = 0; p < 8; ++p)
                    *(uint4*)(outp + (size_t)(bm + hh * 128 + r) * 1024 +
                              colbase + c0 + p * 8) =
                        *(const uint4*)&Ct[r][c0 + p * 8];
            }
            __syncthreads();
        }
    } else {
        const int nbase = bn - 2048;
        for (int hh = 0; hh < 2; ++hh) {
            if ((wc >> 1) == hh) {
#pragma unroll
                for (int m = 0; m < 8; ++m)
#pragma unroll
                    for (int n = 0; n < 4; ++n)
#pragma unroll
                        for (int g = 0; g < 4; ++g)
                            Ct[wc * 64 + n * 16 + l16 - hh * 128]
                              [wr * 128 + m * 16 + quad * 4 + g] =
                                f2bf(acc[m][n][g]);
            }
            __syncthreads();
            {
                const int r = t >> 2, c0 = (t & 3) * 64;
#pragma unroll
                for (int p = 0; p < 8; ++p)
                    *(uint4*)(Vt + (size_t)(nbase + hh * 128 + r) * 4096 +
                              bm + c0 + p * 8) =
                        *(const uint4*)&Ct[r][c0 + p * 8];
            }
            __syncthreads();
        }
    }
}

// ---------------------------------------------------------------------------
// O-projection GEMM, m97-style: A = Y [4096][1024] bf16, W = wob, C fp32.
// ---------------------------------------------------------------------------
__global__ __launch_bounds__(256) void gemm_o(const short* __restrict__ A,
                                              const short* __restrict__ W,
                                              float* __restrict__ C) {
    __shared__ __align__(16) char pool[34816];
    short (*As)[64] = (short(*)[64])pool;             // 128x64 = 16384 B
    short (*Bs)[64] = (short(*)[64])(pool + 16384);   //  64x64 =  8192 B
    const int t    = threadIdx.x;
    const int wave = t >> 6, lane = t & 63, quad = lane >> 4, l16 = lane & 15;
    const int bm = blockIdx.x * 128, bn = blockIdx.y * 64;
    const int qm = (wave >> 1) * 64, qn = (wave & 1) * 32;

    const int lrow = lane >> 3, lcol = (lane & 7) * 8;
    const short* Ag = A + (size_t)(bm + wave * 32 + lrow) * 1024 + lcol;
    const short* Wg = W + (size_t)(bn + wave * 16 + lrow) * 1024 + lcol;
    short* Al = &As[wave * 32][0];
    short* Bl = &Bs[wave * 16][0];

    floatx4 acc[4][2];
#pragma unroll
    for (int i = 0; i < 4; ++i)
#pragma unroll
        for (int j = 0; j < 2; ++j) {
            floatx4 z = {0.f, 0.f, 0.f, 0.f};
            acc[i][j] = z;
        }

    for (int k0 = 0; k0 < 1024; k0 += 64) {
        __syncthreads();
#pragma unroll
        for (int j = 0; j < 4; ++j)
            GLDS(Ag + k0 + (size_t)j * 8 * 1024, Al + j * 8 * 64);
#pragma unroll
        for (int j = 0; j < 2; ++j)
            GLDS(Wg + k0 + (size_t)j * 8 * 1024, Bl + j * 8 * 64);
        __syncthreads();
#pragma unroll
        for (int kk = 0; kk < 64; kk += 32) {
            bhalf8 af[4], bfr[2];
#pragma unroll
            for (int im = 0; im < 4; ++im)
                af[im] = *(const bhalf8*)&As[qm + im * 16 + l16][kk + quad * 8];
#pragma unroll
            for (int jn = 0; jn < 2; ++jn)
                bfr[jn] = *(const bhalf8*)&Bs[qn + jn * 16 + l16][kk + quad * 8];
#pragma unroll
            for (int im = 0; im < 4; ++im)
#pragma unroll
                for (int jn = 0; jn < 2; ++jn)
                    acc[im][jn] = __builtin_amdgcn_mfma_f32_16x16x32_bf16(
                        af[im], bfr[jn], acc[im][jn], 0, 0, 0);
        }
    }

    // ---- fp32 LDS epilogue, line-complete stores ----
    __syncthreads();
    float (*Ctf)[68] = (float(*)[68])pool;            // 128x68x4 = 34816 B
#pragma unroll
    for (int im = 0; im < 4; ++im)
#pragma unroll
        for (int jn = 0; jn < 2; ++jn)
#pragma unroll
            for (int g = 0; g < 4; ++g)
                Ctf[qm + im * 16 + quad * 4 + g][qn + jn * 16 + l16] = acc[im][jn][g];
    __syncthreads();
#pragma unroll
    for (int pass = 0; pass < 8; ++pass) {
        const int r = (t >> 4) + pass * 16;
        const int c = (t & 15) * 4;
        float4 u = *(const float4*)&Ctf[r][c];
        *(float4*)(C + (size_t)(bm + r) * 1024 + bn + c) = u;
    }
}

// ---------------------------------------------------------------------------
// Flash attention v17 — swapped QK^T + k-permuted PV: P never touches LDS.
// v13-v16 invariance (52.8-57.9 us across occupancy/phases/KVBLK/buffering)
// localizes the cost to the chunk body's serial chain, whose only DS RAW is
// the Ps write->read round-trip. v17 eliminates Ps entirely:
//  - S^T = mfma(kf, qf) (args SWAPPED; fragments identical to v13's loads):
//    lane (l16,quad) holds S[k=jn*16+quad*4+g][q=l16] — 16 k for ONE q.
//  - PV contracts over k; permuting k consistently in P AND V preserves the
//    sum. pi(quad*8+j) = (j>>2)*16+quad*4+(j&3) makes the PV A-fragment the
//    lane's own e-registers: af0 = pack(e[0][0..3],e[1][0..3]) via 4 cvt_pk;
//    af1 from e[2],e[3]. V B-fragment under the same pi = two ds_read_b64
//    per frag from the existing Vs[d][k] layout (rows quad*4 and 16+quad*4).
//  - lsum is per-lane (q=l16): final reduce = shfl_xor(16)+shfl_xor(32);
//    redistribution to output rows (q=quad*4+g) via 4 shfl in the epilogue.
//  - Output C-layout (q=quad*4+g, d=nd*16+l16) identical to v13's verified
//    epilogue. Ps (36.8 KB) deleted -> LDS 36864 B.
// Grid 512 (v14's heavy/light split, bid%8 = bh%8 XCD-tied), K/V dbuf,
// 2-chunk-ahead register prefetch, 2 barriers/chunk — all v14-proven.
// ---------------------------------------------------------------------------

__global__ __launch_bounds__(512) void attn_v17(const short* __restrict__ Qo,
                                                const short* __restrict__ Ko,
                                                const short* __restrict__ Vt,
                                                short* __restrict__ Y) {
    __shared__ __align__(16) short Ks[2][64][72];   // 18432 B, K chunk dbuf
    __shared__ __align__(16) short Vs[2][64][72];   // 18432 B, V^T chunk dbuf

    const int t    = threadIdx.x;
    const int wave = t >> 6, lane = t & 63, quad = lane >> 4, l16 = lane & 15;
    const int bid  = (int)blockIdx.x;
    const int bh   = bid & 31;                      // bid%8 = bh%8: XCD-tied
    const int p    = (bid & 255) >> 5;              // 0..7
    const int qt   = (bid < 256) ? (15 - p) : p;    // heavy half, then light
    const int b = bh >> 4, h = bh & 15;
    const int nc   = (qt + 1) * 2;                  // 64-k chunks

    const short* Qbase = Qo + (size_t)b * SEQ * 1024 + h * 64;
    const short* Kbase = Ko + (size_t)b * SEQ * 1024 + h * 64;
    const short* Vbase = Vt + (size_t)h * 64 * 4096 + (size_t)b * SEQ;

    const int sr = t >> 3;            // staging row 0..63
    const int sc = (t & 7) * 8;       // staging col (elements)

    const float KS = 0.125f * 1.44269504f;   // score scale * log2(e)
    const float CB = 12.0f * 1.44269504f;    // fixed softmax offset

    const int qw_  = qt * 128 + wave * 16;   // wave's 16 q-rows
    const int qrow = qw_ + l16;              // this lane's softmax q-row
    const short* qr = Qbase + (size_t)qrow * 1024;
    bhalf8 qf0 = *(const bhalf8*)(qr + quad * 8);
    bhalf8 qf1 = *(const bhalf8*)(qr + 32 + quad * 8);

    float lsum = 0.f;
    floatx4 o[4];
#pragma unroll
    for (int nd = 0; nd < 4; ++nd) {
        floatx4 z = {0.f, 0.f, 0.f, 0.f};
        o[nd] = z;
    }

    uint4 kreg, vreg;
    kreg = *(const uint4*)(Kbase + (size_t)sr * 1024 + sc);
    vreg = *(const uint4*)(Vbase + (size_t)sr * 4096 + sc);
    *(uint4*)&Ks[0][sr][sc] = kreg;
    *(uint4*)&Vs[0][sr][sc] = vreg;
    if (nc > 1) {
        kreg = *(const uint4*)(Kbase + (size_t)(64 + sr) * 1024 + sc);
        vreg = *(const uint4*)(Vbase + (size_t)sr * 4096 + 64 + sc);
    }
    __syncthreads();

#pragma unroll 1
    for (int i = 0; i < nc; ++i) {
        const int buf = i & 1;
        if (i + 1 < nc) {                    // write prefetched chunk i+1
            *(uint4*)&Ks[buf ^ 1][sr][sc] = kreg;
            *(uint4*)&Vs[buf ^ 1][sr][sc] = vreg;
        }
        if (i + 2 < nc) {                    // T14: chunk i+2 -> regs
            const int kn = (i + 2) * 64;
            kreg = *(const uint4*)(Kbase + (size_t)(kn + sr) * 1024 + sc);
            vreg = *(const uint4*)(Vbase + (size_t)sr * 4096 + kn + sc);
        }
        const int k0 = i * 64;
        if (k0 <= qw_ + 15) {                // wave-uniform: skip fully-masked
            // ---- S^T = K Q^T (swapped args; fragments as in v13) ----
            bhalf8 kf[4][2];
#pragma unroll
            for (int jn = 0; jn < 4; ++jn) {
                kf[jn][0] = *(const bhalf8*)&Ks[buf][jn * 16 + l16][quad * 8];
                kf[jn][1] = *(const bhalf8*)&Ks[buf][jn * 16 + l16][32 + quad * 8];
            }
            floatx4 s_[4];
#pragma unroll
            for (int jn = 0; jn < 4; ++jn) {
                floatx4 z = {0.f, 0.f, 0.f, 0.f};
                z = MFMA_BF16(kf[jn][0], qf0, z, 0, 0, 0);
                z = MFMA_BF16(kf[jn][1], qf1, z, 0, 0, 0);
                s_[jn] = z;                  // lane: S[k0+jn*16+quad*4+g][qrow]
            }
            // ---- softmax in registers (fixed-CB) ----
            const bool partial = (k0 + 64 > qw_);
            float e[4][4];
#pragma unroll
            for (int jn = 0; jn < 4; ++jn)
#pragma unroll
                for (int g = 0; g < 4; ++g) {
                    float v = exp2f(s_[jn][g] * KS - CB);
                    if (partial && (k0 + jn * 16 + quad * 4 + g > qrow)) v = 0.f;
                    e[jn][g] = v;
                    lsum += v;
                }
            // ---- pack P fragments (pi-permuted k; lane-local, no LDS) ----
            uint4v w0 = {cvt_pk_bf16(e[0][0], e[0][1]), cvt_pk_bf16(e[0][2], e[0][3]),
                         cvt_pk_bf16(e[1][0], e[1][1]), cvt_pk_bf16(e[1][2], e[1][3])};
            uint4v w1 = {cvt_pk_bf16(e[2][0], e[2][1]), cvt_pk_bf16(e[2][2], e[2][3]),
                         cvt_pk_bf16(e[3][0], e[3][1]), cvt_pk_bf16(e[3][2], e[3][3])};
            bhalf8 af0 = __builtin_bit_cast(bhalf8, w0);
            bhalf8 af1 = __builtin_bit_cast(bhalf8, w1);
            // ---- O += P V with the same pi on V's k-rows (2x b64 per frag) ----
#pragma unroll
            for (int nd = 0; nd < 4; ++nd) {
                const short* vrow = &Vs[buf][nd * 16 + l16][0];
                bhalf8 vf0, vf1;
                *(short4v*)&vf0       = *(const short4v*)(vrow + quad * 4);
                *((short4v*)&vf0 + 1) = *(const short4v*)(vrow + 16 + quad * 4);
                *(short4v*)&vf1       = *(const short4v*)(vrow + 32 + quad * 4);
                *((short4v*)&vf1 + 1) = *(const short4v*)(vrow + 48 + quad * 4);
                o[nd] = MFMA_BF16(af0, vf0, o[nd], 0, 0, 0);
                o[nd] = MFMA_BF16(af1, vf1, o[nd], 0, 0, 0);
            }
        }
        __syncthreads();
    }

    // ---- lsum reduce over quads, redistribute, store ----
    lsum += __shfl_xor(lsum, 16, 64);
    lsum += __shfl_xor(lsum, 32, 64);        // all lanes with l16=q hold total
#pragma unroll
    for (int g = 0; g < 4; ++g) {
        const float r  = __shfl(lsum, quad * 4 + g, 64);
        const float iv = 1.0f / r;
        const int qrow_o = qw_ + quad * 4 + g;
#pragma unroll
        for (int nd = 0; nd < 4; ++nd)
            Y[(size_t)(b * SEQ + qrow_o) * 1024 + h * 64 + nd * 16 + l16] =
                f2bf(o[nd][g] * iv);
    }
}

// ---------------------------------------------------------------------------
extern "C" void kernel_launch(void* const* d_in, const int* in_sizes, int n_in,
                              void* d_out, int out_size, void* d_ws, size_t ws_size,
                              hipStream_t stream) {
    const float* x  = (const float*)d_in[0];
    const float* wq = (const float*)d_in[1];
    const float* wk = (const float*)d_in[2];
    const float* wv = (const float*)d_in[3];
    const float* wo = (const float*)d_in[4];

    short* xb   = (short*)d_ws;
    short* Qo   = xb + (size_t)4096 * 1024;
    short* Ko   = Qo + (size_t)4096 * 1024;
    short* Vt   = Ko + (size_t)4096 * 1024;
    short* wall = Vt + (size_t)1024 * 4096;
    short* wob  = wall + (size_t)3 * 1024 * 1024;

    cast_all<<<dim3(4096), 256, 0, stream>>>(x, wq, wk, wv, wo, xb, wall);
    gemm_qkv2<<<dim3(16, 12), 512, 0, stream>>>(xb, wall, Qo, Ko, Vt);
    attn_v17<<<dim3(512), 512, 0, stream>>>(Qo, Ko, Vt, xb);
    gemm_o<<<dim3(32, 16), 256, 0, stream>>>(xb, wob, (float*)d_out);
}